// Round 1
// baseline (2395.967 us; speedup 1.0000x reference)
//
#include <hip/hip_runtime.h>

#define HID 32
#define EPB 128   // elements per block (2 threads per element, 256-thread blocks)

__device__ __forceinline__ float sigmoidf_fast(float x) {
    return __fdividef(1.0f, 1.0f + __expf(-x));
}
__device__ __forceinline__ float tanhf_fast(float x) {
    // tanh(x) = 1 - 2/(1 + e^{2x}); saturates correctly at +/-inf
    return 1.0f - __fdividef(2.0f, 1.0f + __expf(2.0f * x));
}

__global__ __launch_bounds__(256, 2)
void lstm_dyn_kernel(const float* __restrict__ poses,
                     const float* __restrict__ W_ih,
                     const float* __restrict__ W_hh,
                     const float* __restrict__ W_dense,
                     float* __restrict__ out,
                     int B, int T_enc, int T_dec)
{
    // [j][elem] layout: lanes (consecutive elems) hit consecutive banks -> 2-way, free
    __shared__ float c_lds [HID][EPB];
    __shared__ float hn_lds[HID][EPB];

    const int tid = threadIdx.x;
    const int elb = tid & (EPB - 1);
    // sub is wave-uniform (flips at lane 128); readfirstlane forces the compiler's
    // uniformity analysis to see it, so weight indices become uniform -> s_load path.
    const int sub = __builtin_amdgcn_readfirstlane(tid >> 7);   // 0 or 1
    const int j0  = sub * 16;
    const int el  = blockIdx.x * EPB + elb;

    const float4* poses4 = reinterpret_cast<const float4*>(poses);
    const float4* Wih4   = reinterpret_cast<const float4*>(W_ih);
    float4*       out4   = reinterpret_cast<float4*>(out);

    float h[HID];
    #pragma unroll
    for (int k = 0; k < HID; ++k) h[k] = 0.0f;
    #pragma unroll
    for (int jj = 0; jj < 16; ++jj) c_lds[j0 + jj][elb] = 0.0f;
    // c_lds slots are private to their owning thread; hn_lds is guarded by barriers below.

    auto lstm_step = [&](float4 x) {
        #pragma unroll 2
        for (int jj = 0; jj < 16; ++jj) {
            const int j = j0 + jj;
            const float4 wi = Wih4[j];
            const float4 wf = Wih4[j + 32];
            const float4 wg = Wih4[j + 64];
            const float4 wo = Wih4[j + 96];
            float gi = wi.x * x.x + wi.y * x.y + wi.z * x.z + wi.w * x.w;
            float gf = wf.x * x.x + wf.y * x.y + wf.z * x.z + wf.w * x.w;
            float gg = wg.x * x.x + wg.y * x.y + wg.z * x.z + wg.w * x.w;
            float go = wo.x * x.x + wo.y * x.y + wo.z * x.z + wo.w * x.w;
            #pragma unroll
            for (int k = 0; k < HID; ++k) {
                gi = fmaf(W_hh[(j     ) * HID + k], h[k], gi);
                gf = fmaf(W_hh[(j + 32) * HID + k], h[k], gf);
                gg = fmaf(W_hh[(j + 64) * HID + k], h[k], gg);
                go = fmaf(W_hh[(j + 96) * HID + k], h[k], go);
            }
            const float ii = sigmoidf_fast(gi);
            const float ff = sigmoidf_fast(gf);
            const float g2 = tanhf_fast(gg);
            const float oo = sigmoidf_fast(go);
            const float cn = ff * c_lds[j][elb] + ii * g2;
            c_lds[j][elb]  = cn;
            hn_lds[j][elb] = oo * tanhf_fast(cn);
        }
        __syncthreads();
        #pragma unroll
        for (int k = 0; k < HID; ++k) h[k] = hn_lds[k][elb];
        __syncthreads();   // protect hn_lds from next step's writes until both readers done
    };

    // ---------------- encoder ----------------
    float4 x = make_float4(0.f, 0.f, 0.f, 0.f);
    for (int t = 0; t < T_enc; ++t) {
        x = poses4[(size_t)t * B + el];   // coalesced 16B/lane
        lstm_step(x);
    }
    const float px = x.x;   // last_pose[:2] — constant for the whole decode
    const float py = x.y;

    // initial velocity rows 1,2 of W_dense (row 0 unused by the reference)
    float v1 = 0.f, v2 = 0.f;
    #pragma unroll
    for (int k = 0; k < HID; ++k) {
        v1 = fmaf(W_dense[1 * HID + k], h[k], v1);
        v2 = fmaf(W_dense[2 * HID + k], h[k], v2);
    }

    // ---------------- decoder ----------------
    for (int t = 0; t < T_dec; ++t) {
        const float rn = rsqrtf(v1 * v1 + v2 * v2);
        const float cs = v1 * rn;
        const float sn = v2 * rn;
        const float4 np4 = make_float4(px, py, cs, sn);
        if (sub == 0) out4[(size_t)t * B + el] = np4;   // one writer per element
        lstm_step(np4);
        v1 = 0.f; v2 = 0.f;
        #pragma unroll
        for (int k = 0; k < HID; ++k) {
            v1 = fmaf(W_dense[1 * HID + k], h[k], v1);
            v2 = fmaf(W_dense[2 * HID + k], h[k], v2);
        }
    }
}

extern "C" void kernel_launch(void* const* d_in, const int* in_sizes, int n_in,
                              void* d_out, int out_size, void* d_ws, size_t ws_size,
                              hipStream_t stream) {
    const float* poses   = (const float*)d_in[0];
    // d_in[1] = deltas: values unused by the reference decoder (only its length matters)
    const float* W_ih    = (const float*)d_in[2];
    const float* W_hh    = (const float*)d_in[3];
    const float* W_dense = (const float*)d_in[4];
    float* out = (float*)d_out;

    const int T_enc = 64;                       // fixed by the reference setup
    const int B     = in_sizes[0] / (T_enc * 4);
    const int T_dec = out_size / (B * 4);       // n_new_poses

    dim3 grid(B / EPB), block(256);
    hipLaunchKernelGGL(lstm_dyn_kernel, grid, block, 0, stream,
                       poses, W_ih, W_hh, W_dense, out, B, T_enc, T_dec);
}

// Round 2
// 1678.568 us; speedup vs baseline: 1.4274x; 1.4274x over previous
//
#include <hip/hip_runtime.h>

typedef float v2f __attribute__((ext_vector_type(2)));

#define HID 32

__device__ __forceinline__ float sigmoidf_fast(float x) {
    return __fdividef(1.0f, 1.0f + __expf(-x));
}
__device__ __forceinline__ float tanhf_fast(float x) {
    // tanh(x) = 1 - 2/(1+e^{2x}); saturates correctly
    return 1.0f - __fdividef(2.0f, 1.0f + __expf(2.0f * x));
}

// xor-butterfly add within 32-lane groups (ds_swizzle bit-mode, and=0x1F)
#define SWZ_ADD(p, imm) do {                                            \
    int _t = __builtin_amdgcn_ds_swizzle(__float_as_int(p), (imm));     \
    (p) += __int_as_float(_t); } while (0)
#define REDUCE32(p) do {                                                \
    SWZ_ADD(p, 0x041F); SWZ_ADD(p, 0x081F); SWZ_ADD(p, 0x101F);        \
    SWZ_ADD(p, 0x201F); SWZ_ADD(p, 0x401F); } while (0)

__global__ __launch_bounds__(256, 2)
void lstm_persist(const float* __restrict__ poses,
                  const float* __restrict__ W_ih,
                  const float* __restrict__ W_hh,
                  const float* __restrict__ W_dense,
                  float* __restrict__ out,
                  int B, int T_enc, int T_dec)
{
    // 8 elements per 256-thread block, 32 lanes per element.
    // hx[eb][*]: intra-half-wave h exchange. Writes: lanes 0..31 -> banks 0..31,
    // two half-waves alias 2-way (free, m136). Reads: 16B broadcast per half-wave.
    __shared__ __align__(16) float hx[8][HID];

    const int tid = threadIdx.x;
    const int k   = tid & 31;          // hidden unit owned by this lane
    const int eb  = tid >> 5;          // element within block (0..7)
    const int el  = blockIdx.x * 8 + eb;

    // ---- persistent register weights: rows k, k+32, k+64, k+96 ----
    const float4* Wih4 = reinterpret_cast<const float4*>(W_ih);
    const float4 wi4 = Wih4[k], wf4 = Wih4[k + 32], wg4 = Wih4[k + 64], wo4 = Wih4[k + 96];
    const v2f wi01 = {wi4.x, wi4.y}, wi23 = {wi4.z, wi4.w};
    const v2f wf01 = {wf4.x, wf4.y}, wf23 = {wf4.z, wf4.w};
    const v2f wg01 = {wg4.x, wg4.y}, wg23 = {wg4.z, wg4.w};
    const v2f wo01 = {wo4.x, wo4.y}, wo23 = {wo4.z, wo4.w};

    v2f whh_i[16], whh_f[16], whh_g[16], whh_o[16];   // 128 VGPRs, loaded once
    {
        const v2f* Whh2 = reinterpret_cast<const v2f*>(W_hh);
        #pragma unroll
        for (int j = 0; j < 16; ++j) {
            whh_i[j] = Whh2[(k     ) * 16 + j];
            whh_f[j] = Whh2[(k + 32) * 16 + j];
            whh_g[j] = Whh2[(k + 64) * 16 + j];
            whh_o[j] = Whh2[(k + 96) * 16 + j];
        }
    }
    const float wd1 = W_dense[HID + k];
    const float wd2 = W_dense[2 * HID + k];

    v2f h2[16];
    #pragma unroll
    for (int j = 0; j < 16; ++j) h2[j] = (v2f){0.f, 0.f};
    float c = 0.f, hk = 0.f;

    const float4* poses4 = reinterpret_cast<const float4*>(poses);
    float4*       out4   = reinterpret_cast<float4*>(out);

    auto lstm_step = [&](float xx, float xy, float xz, float xw) {
        const v2f x01 = {xx, xy}, x23 = {xz, xw};
        v2f ai = wi01 * x01 + wi23 * x23;
        v2f af = wf01 * x01 + wf23 * x23;
        v2f ag = wg01 * x01 + wg23 * x23;
        v2f ao = wo01 * x01 + wo23 * x23;
        #pragma unroll
        for (int j = 0; j < 16; ++j) {      // 4 independent pk_fma chains
            ai += whh_i[j] * h2[j];
            af += whh_f[j] * h2[j];
            ag += whh_g[j] * h2[j];
            ao += whh_o[j] * h2[j];
        }
        const float gi = ai.x + ai.y, gf = af.x + af.y;
        const float gg = ag.x + ag.y, go = ao.x + ao.y;
        const float ii = sigmoidf_fast(gi);
        const float ff = sigmoidf_fast(gf);
        const float gt = tanhf_fast(gg);
        const float oo = sigmoidf_fast(go);
        c  = ff * c + ii * gt;              // c stays in this lane forever
        hk = oo * tanhf_fast(c);
        // intra-wave h exchange: no barrier needed (half-wave private row)
        hx[eb][k] = hk;
        const float4* hr = reinterpret_cast<const float4*>(&hx[eb][0]);
        #pragma unroll
        for (int j = 0; j < 8; ++j) {
            const float4 v = hr[j];         // broadcast ds_read_b128
            h2[2*j]     = (v2f){v.x, v.y};
            h2[2*j + 1] = (v2f){v.z, v.w};
        }
    };

    // ---------------- encoder (x prefetched one step ahead) ----------------
    float4 x = poses4[el];
    for (int t = 0; t < T_enc; ++t) {
        float4 xn = x;
        if (t + 1 < T_enc) xn = poses4[(size_t)(t + 1) * B + el];
        lstm_step(x.x, x.y, x.z, x.w);
        x = xn;
    }
    const float px = x.x, py = x.y;         // poses[-1][:,:2], constant in decode

    float v1 = wd1 * hk, v2 = wd2 * hk;     // vel rows 1,2 (row 0 unused)
    REDUCE32(v1); REDUCE32(v2);

    // ---------------- decoder ----------------
    for (int t = 0; t < T_dec; ++t) {
        const float rn = rsqrtf(v1 * v1 + v2 * v2);
        const float cs = v1 * rn, sn = v2 * rn;
        if (k == 0) out4[(size_t)t * B + el] = make_float4(px, py, cs, sn);
        lstm_step(px, py, cs, sn);
        v1 = wd1 * hk; v2 = wd2 * hk;
        REDUCE32(v1); REDUCE32(v2);
    }
}

extern "C" void kernel_launch(void* const* d_in, const int* in_sizes, int n_in,
                              void* d_out, int out_size, void* d_ws, size_t ws_size,
                              hipStream_t stream) {
    const float* poses   = (const float*)d_in[0];
    // d_in[1] = deltas: values unused by the reference decoder (only length matters)
    const float* W_ih    = (const float*)d_in[2];
    const float* W_hh    = (const float*)d_in[3];
    const float* W_dense = (const float*)d_in[4];
    float* out = (float*)d_out;

    const int T_enc = 64;                       // fixed by the reference setup
    const int B     = in_sizes[0] / (T_enc * 4);
    const int T_dec = out_size / (B * 4);       // n_new_poses

    dim3 grid(B / 8), block(256);
    hipLaunchKernelGGL(lstm_persist, grid, block, 0, stream,
                       poses, W_ih, W_hh, W_dense, out, B, T_enc, T_dec);
}

// Round 3
// 1591.212 us; speedup vs baseline: 1.5057x; 1.0549x over previous
//
#include <hip/hip_runtime.h>

typedef float v4f __attribute__((ext_vector_type(4)));

#define HID 32

__device__ __forceinline__ float sigmoidf_fast(float x) {
    return __fdividef(1.0f, 1.0f + __expf(-x));
}
__device__ __forceinline__ float tanhf_fast(float x) {
    // tanh(x) = 1 - 2/(1+e^{2x}); saturates correctly
    return 1.0f - __fdividef(2.0f, 1.0f + __expf(2.0f * x));
}

// Opaque value barrier: result cannot be rematerialized from memory,
// so the compiler must keep it live in VGPRs across the whole kernel.
#define KEEP4(v) asm volatile("" : "+v"(v))

// xor-butterfly add within 32-lane groups (ds_swizzle bit-mode, and=0x1F)
#define SWZ_ADD(p, imm) do {                                            \
    int _t = __builtin_amdgcn_ds_swizzle(__float_as_int(p), (imm));     \
    (p) += __int_as_float(_t); } while (0)
#define REDUCE32(p) do {                                                \
    SWZ_ADD(p, 0x041F); SWZ_ADD(p, 0x081F); SWZ_ADD(p, 0x101F);        \
    SWZ_ADD(p, 0x201F); SWZ_ADD(p, 0x401F); } while (0)

__global__ __launch_bounds__(256, 2)
void lstm_persist(const float* __restrict__ poses,
                  const float* __restrict__ W_ih,
                  const float* __restrict__ W_hh,
                  const float* __restrict__ W_dense,
                  float* __restrict__ out,
                  int B, int T_enc, int T_dec)
{
    // 8 elements per 256-thread block, 32 lanes per element.
    __shared__ __align__(16) float hx[8][HID];

    const int tid = threadIdx.x;
    const int k   = tid & 31;          // hidden unit owned by this lane
    const int eb  = tid >> 5;          // element within block (0..7)
    const int el  = blockIdx.x * 8 + eb;

    // ---- persistent register weights: rows k, k+32, k+64, k+96 ----
    const v4f* Wih4 = reinterpret_cast<const v4f*>(W_ih);
    v4f wi4 = Wih4[k], wf4 = Wih4[k + 32], wg4 = Wih4[k + 64], wo4 = Wih4[k + 96];

    v4f whh_i[8], whh_f[8], whh_g[8], whh_o[8];   // 128 VGPRs, loaded ONCE
    {
        const v4f* Whh4 = reinterpret_cast<const v4f*>(W_hh);
        #pragma unroll
        for (int j = 0; j < 8; ++j) {
            whh_i[j] = Whh4[(k     ) * 8 + j];
            whh_f[j] = Whh4[(k + 32) * 8 + j];
            whh_g[j] = Whh4[(k + 64) * 8 + j];
            whh_o[j] = Whh4[(k + 96) * 8 + j];
        }
    }
    // Pin everything in VGPRs (no remat / per-step reload).
    #pragma unroll
    for (int j = 0; j < 8; ++j) {
        KEEP4(whh_i[j]); KEEP4(whh_f[j]); KEEP4(whh_g[j]); KEEP4(whh_o[j]);
    }
    KEEP4(wi4); KEEP4(wf4); KEEP4(wg4); KEEP4(wo4);

    const float wd1 = W_dense[HID + k];
    const float wd2 = W_dense[2 * HID + k];

    v4f h4[8];
    #pragma unroll
    for (int j = 0; j < 8; ++j) h4[j] = (v4f){0.f, 0.f, 0.f, 0.f};
    float c = 0.f, hk = 0.f;

    const v4f* poses4 = reinterpret_cast<const v4f*>(poses);
    v4f*       out4   = reinterpret_cast<v4f*>(out);

    auto lstm_step = [&](v4f x4) {
        v4f ai = wi4 * x4;                  // W_ih part folds into the same
        v4f af = wf4 * x4;                  // horizontal sum as W_hh
        v4f ag = wg4 * x4;
        v4f ao = wo4 * x4;
        #pragma unroll
        for (int j = 0; j < 8; ++j) {       // 4 independent v_pk_fma_f32 chains
            ai += whh_i[j] * h4[j];
            af += whh_f[j] * h4[j];
            ag += whh_g[j] * h4[j];
            ao += whh_o[j] * h4[j];
        }
        const float gi = (ai[0] + ai[1]) + (ai[2] + ai[3]);
        const float gf = (af[0] + af[1]) + (af[2] + af[3]);
        const float gg = (ag[0] + ag[1]) + (ag[2] + ag[3]);
        const float go = (ao[0] + ao[1]) + (ao[2] + ao[3]);
        const float ii = sigmoidf_fast(gi);
        const float ff = sigmoidf_fast(gf);
        const float gt = tanhf_fast(gg);
        const float oo = sigmoidf_fast(go);
        c  = ff * c + ii * gt;              // c stays in this lane forever
        hk = oo * tanhf_fast(c);
        // intra-wave h exchange: half-wave-private row, no barrier needed
        hx[eb][k] = hk;
        #pragma unroll
        for (int j = 0; j < 8; ++j)
            h4[j] = *reinterpret_cast<const v4f*>(&hx[eb][4 * j]);  // broadcast b128
    };

    // ---------------- encoder (x prefetched one step ahead) ----------------
    v4f x = poses4[el];
    for (int t = 0; t < T_enc; ++t) {
        v4f xn = x;
        if (t + 1 < T_enc) xn = poses4[(size_t)(t + 1) * B + el];
        lstm_step(x);
        x = xn;
    }
    const float px = x[0], py = x[1];       // poses[-1][:,:2], constant in decode

    float v1 = wd1 * hk, v2 = wd2 * hk;     // vel rows 1,2 (row 0 unused)
    REDUCE32(v1); REDUCE32(v2);

    // ---------------- decoder ----------------
    for (int t = 0; t < T_dec; ++t) {
        const float rn = rsqrtf(v1 * v1 + v2 * v2);
        const float cs = v1 * rn, sn = v2 * rn;
        if (k == 0) out4[(size_t)t * B + el] = (v4f){px, py, cs, sn};
        lstm_step((v4f){px, py, cs, sn});
        v1 = wd1 * hk; v2 = wd2 * hk;
        REDUCE32(v1); REDUCE32(v2);
    }
}

extern "C" void kernel_launch(void* const* d_in, const int* in_sizes, int n_in,
                              void* d_out, int out_size, void* d_ws, size_t ws_size,
                              hipStream_t stream) {
    const float* poses   = (const float*)d_in[0];
    // d_in[1] = deltas: values unused by the reference decoder (only length matters)
    const float* W_ih    = (const float*)d_in[2];
    const float* W_hh    = (const float*)d_in[3];
    const float* W_dense = (const float*)d_in[4];
    float* out = (float*)d_out;

    const int T_enc = 64;                       // fixed by the reference setup
    const int B     = in_sizes[0] / (T_enc * 4);
    const int T_dec = out_size / (B * 4);       // n_new_poses

    dim3 grid(B / 8), block(256);
    hipLaunchKernelGGL(lstm_persist, grid, block, 0, stream,
                       poses, W_ih, W_hh, W_dense, out, B, T_enc, T_dec);
}